// Round 6
// baseline (145.699 us; speedup 1.0000x reference)
//
#include <hip/hip_runtime.h>
#include <stdint.h>

// Problem constants (from reference):
//   features: [128, 16384, 6] f32; mask_token: [6] f32; seed 1234
//   MASK_RATIO=0.15 -> target_masked = int(16384*0.15) = 2457
//   n_spans = max(1, int(2457/12.5*2)) = 393
constexpr int NB = 128;
constexpr int SEQ = 16384;
constexpr int NF = 6;
constexpr int NSPANS = 393;
constexpr uint32_t TGT = 2457u;
constexpr int ROWF = SEQ * NF;          // 98304 floats per row
constexpr int ROWF4 = ROWF / 4;         // 24576 float4 per row
constexpr int TOT4 = NB * ROWF4;        // 3145728 float4 total

// ---- workspace layout (dword offsets) ----
constexpr int FM_OFF = 0;                           // 128*512 final mask bits
constexpr int FM_DW = NB * (SEQ / 32);              // 65536
constexpr int SC_OFF = FM_OFF + FM_DW;              // 128*16384 scores
constexpr int SC_DW = NB * SEQ;                     // 2097152
constexpr int PH_OFF = SC_OFF + SC_DW;              // 512*4096 partial hists
constexpr int PH_DW = NB * 4 * 4096;                // 2097152
constexpr size_t WS_BYTES = (size_t)(PH_OFF + PH_DW) * 4;  // ~17 MB

struct Keys {
  uint32_t klo0, klo1;     // randint(k_len) child-2 key (span=16 pow2: only lower bits matter)
  uint32_t khi_s0, khi_s1; // randint(k_start) child-1 key -> higher bits
  uint32_t klo_s0, klo_s1; // randint(k_start) child-2 key -> lower bits
  uint32_t kn0, kn1;       // k_noise
};

// JAX threefry2x32 (20 rounds)
__host__ __device__ inline void tf2x32(uint32_t k0, uint32_t k1,
                                       uint32_t x0, uint32_t x1,
                                       uint32_t& o0, uint32_t& o1) {
  uint32_t ks[3] = {k0, k1, k0 ^ k1 ^ 0x1BD11BDAu};
  uint32_t a = x0 + ks[0], b = x1 + ks[1];
  const uint32_t rot[2][4] = {{13u,15u,26u,6u},{17u,29u,16u,24u}};
#pragma unroll
  for (int i = 0; i < 5; ++i) {
    const uint32_t* r = rot[i & 1];
#pragma unroll
    for (int j = 0; j < 4; ++j) {
      a += b;
      b = (b << r[j]) | (b >> (32u - r[j]));
      b ^= a;
    }
    a += ks[(i + 1) % 3];
    b += ks[(i + 2) % 3] + (uint32_t)(i + 1);
  }
  o0 = a; o1 = b;
}

// JAX partitionable random_bits (32-bit): bits[j] = a ^ b, (a,b) = tf(key, (0, j))
__device__ inline uint32_t rbits(uint32_t k0, uint32_t k1, uint32_t j) {
  uint32_t o0, o1;
  tf2x32(k0, k1, 0u, j, o0, o1);
  return o0 ^ o1;
}

// =============== K1: scores + partial histograms, 4 blocks per row ===============
// Each block: paint full row coverage in LDS (all 393 spans), score its 4096
// positions (1 threefry each), LDS level-1 histogram, write scores + partial hist.
__global__ __launch_bounds__(256)
void score_hist_kernel(uint32_t* __restrict__ ws, Keys K) {
  __shared__ uint32_t cov[SEQ / 32];   // 2 KB
  __shared__ uint32_t hist[4096];      // 16 KB
  const int t = threadIdx.x;
  const uint32_t bi = blockIdx.x;      // 0..511
  const uint32_t b = bi >> 2;
  const uint32_t q = bi & 3u;

  for (int i = t; i < 4096; i += 256) hist[i] = 0u;
  for (int i = t; i < SEQ / 32; i += 256) cov[i] = 0u;
  __syncthreads();

  // spans (full row; clipping-free)
  for (int i = t; i < NSPANS; i += 256) {
    uint32_t j = b * (uint32_t)NSPANS + (uint32_t)i;
    uint32_t lenb = rbits(K.klo0, K.klo1, j);
    uint32_t len = 5u + (lenb & 15u);
    uint32_t hb = rbits(K.khi_s0, K.khi_s1, j);
    uint32_t lb = rbits(K.klo_s0, K.klo_s1, j);
    const uint32_t span = 16379u;       // 2^32 % 16379 = 400
    uint32_t start = ((hb % span) * 400u + (lb % span)) % span;
    uint32_t end = start + len; if (end > (uint32_t)SEQ) end = SEQ;
    uint32_t w0 = start >> 5, w1 = (end - 1u) >> 5;
    for (uint32_t w = w0; w <= w1; ++w) {
      uint32_t bs = (w == w0) ? (start & 31u) : 0u;
      uint32_t be = (w == w1) ? ((end - 1u) & 31u) : 31u;
      uint32_t n = be - bs + 1u;
      uint32_t m = (n >= 32u) ? 0xFFFFFFFFu : (((1u << n) - 1u) << bs);
      atomicOr(&cov[w], m);
    }
  }
  __syncthreads();

  // scores for my quarter
  const uint32_t base = q << 12;
  const uint32_t jb = (b << 14) + base;
  uint32_t* sc = ws + SC_OFF + (b << 14) + base;
#pragma unroll 4
  for (int i = 0; i < 16; ++i) {
    int s = (i << 8) + t;               // 0..4095 within quarter
    int gs = (int)base + s;             // position in row
    uint32_t bits = rbits(K.kn0, K.kn1, jb + (uint32_t)s);
    uint32_t si = (bits >> 9) + (((cov[gs >> 5] >> (gs & 31)) & 1u) << 23);
    sc[s] = si;
    atomicAdd(&hist[si >> 12], 1u);
  }
  __syncthreads();

  uint32_t* ph = ws + PH_OFF + (bi << 12);
  for (int i = t; i < 4096; i += 256) ph[i] = hist[i];
}

// =============== K2: per-row two-level radix select -> mask bits ===============
// (R3-validated select_kernel; level-1 hist = sum of 4 partial hists.)
__global__ __launch_bounds__(256)
void select_kernel(uint32_t* __restrict__ ws) {
  __shared__ uint32_t h[4096];
  __shared__ uint32_t part[256];
  __shared__ uint32_t fm[SEQ / 32];
  __shared__ int tielist[1024];
  __shared__ uint32_t sH, sA, sT, sN;
  __shared__ int tieCnt;

  const int t = threadIdx.x;
  const uint32_t b = blockIdx.x;
  const uint32_t* rs = ws + SC_OFF + (b << 14);
  const uint32_t* ph = ws + PH_OFF + (b << 14);   // 4 hists of 4096

  for (int i = t; i < 4096; i += 256)
    h[i] = ph[i] + ph[4096 + i] + ph[8192 + i] + ph[12288 + i];
  if (t == 0) tieCnt = 0;
  __syncthreads();

  // ---- level 1: find bucket H (descending) s.t. countAbove crosses TGT ----
  {
    uint32_t sum = 0;
#pragma unroll
    for (int i = 0; i < 16; ++i) sum += h[t * 16 + i];
    part[t] = sum;
    __syncthreads();
    for (int off = 1; off < 256; off <<= 1) {
      uint32_t v = (t + off < 256) ? part[t + off] : 0u;
      __syncthreads();
      part[t] += v;
      __syncthreads();
    }
    uint32_t above = (t < 255) ? part[t + 1] : 0u;
    uint32_t mine = part[t];
    if (above < TGT && TGT <= mine) {
      uint32_t run = above;
      for (int hb = t * 16 + 15; hb >= t * 16; --hb) {
        uint32_t c = h[hb];
        if (run + c >= TGT) { sH = (uint32_t)hb; sA = run; break; }
        run += c;
      }
    }
  }
  __syncthreads();
  uint32_t H = sH;
  uint32_t targetB = TGT - sA;

  for (int i = t; i < 4096; i += 256) h[i] = 0u;
  __syncthreads();

  // ---- level 2: histogram low 12 bits within bucket H (scores L2-hot) ----
#pragma unroll 4
  for (int q = 0; q < 64; ++q) {
    uint32_t si = rs[(q << 8) + t];
    if ((si >> 12) == H) atomicAdd(&h[si & 4095u], 1u);
  }
  __syncthreads();
  {
    uint32_t sum = 0;
#pragma unroll
    for (int i = 0; i < 16; ++i) sum += h[t * 16 + i];
    part[t] = sum;
    __syncthreads();
    for (int off = 1; off < 256; off <<= 1) {
      uint32_t v = (t + off < 256) ? part[t + off] : 0u;
      __syncthreads();
      part[t] += v;
      __syncthreads();
    }
    uint32_t above = (t < 255) ? part[t + 1] : 0u;
    uint32_t mine = part[t];
    if (above < targetB && targetB <= mine) {
      uint32_t run = above;
      for (int lb = t * 16 + 15; lb >= t * 16; --lb) {
        uint32_t c = h[lb];
        if (run + c >= targetB) {
          sT = (H << 12) | (uint32_t)lb;
          sN = targetB - run;   // # ties at T accepted (lowest indices first)
          break;
        }
        run += c;
      }
    }
  }
  __syncthreads();
  uint32_t T = sT, need = sN;

  // ---- emit bits: si > T via ballot; collect ties ----
  for (int q = 0; q < 64; ++q) {
    int s = (q << 8) + t;
    uint32_t si = rs[s];
    unsigned long long bal = __ballot(si > T);
    if (si == T) {
      int idx = atomicAdd(&tieCnt, 1);
      if (idx < 1024) tielist[idx] = s;
    }
    int l = t & 63;
    if (l == 0)       fm[s >> 5] = (uint32_t)bal;
    else if (l == 32) fm[s >> 5] = (uint32_t)(bal >> 32);
  }
  __syncthreads();
  int tc = tieCnt > 1024 ? 1024 : tieCnt;
  for (int i = t; i < tc; i += 256) {
    int s = tielist[i];
    uint32_t rank = 0;
    for (int j = 0; j < tc; ++j) rank += (tielist[j] < s) ? 1u : 0u;
    if (rank < need) atomicOr(&fm[s >> 5], 1u << (s & 31));
  }
  __syncthreads();
  uint32_t* fmg = ws + FM_OFF + (b << 9);
  for (int i = t; i < SEQ / 32; i += 256) fmg[i] = fm[i];
}

// =============== K3: apply, LDS-staged fully-coalesced (R5-validated) ===============
__global__ __launch_bounds__(256)
void apply3(const float* __restrict__ feat, const float* __restrict__ tok,
            const uint32_t* __restrict__ ws, float* __restrict__ out) {
  __shared__ float4 tile[768];         // 12 KB
  const int t = threadIdx.x;
  const uint32_t n = blockIdx.x;       // 0..4095
  const float4* f4 = (const float4*)feat + (size_t)n * 768;
  float4* o4 = (float4*)out + (size_t)n * 768;

  tile[t] = f4[t];
  tile[t + 256] = f4[t + 256];
  tile[t + 512] = f4[t + 512];
  uint32_t w = ws[FM_OFF + (n << 4) + (t >> 4)];   // 16 threads share a word
  float t0 = tok[0], t1 = tok[1], t2 = tok[2], t3 = tok[3], t4 = tok[4], t5 = tok[5];
  __syncthreads();

  float* lf = (float*)tile + t * 12;   // my 12 elements = positions p0, p0+1
  uint32_t bit0 = (uint32_t)(2 * t) & 31u;
  bool m0 = (w >> bit0) & 1u;
  bool m1 = (w >> (bit0 + 1u)) & 1u;
  m0 = m0 && !(lf[0] != lf[0]);        // valid = !isnan(channel 0)
  m1 = m1 && !(lf[6] != lf[6]);
  if (m0) { lf[0] = t0; lf[1] = t1; lf[2] = t2; lf[3] = t3; lf[4] = t4; lf[5] = t5; }
  if (m1) { lf[6] = t0; lf[7] = t1; lf[8] = t2; lf[9] = t3; lf[10] = t4; lf[11] = t5; }
  __syncthreads();

  o4[t] = tile[t];
  o4[t + 256] = tile[t + 256];
  o4[t + 512] = tile[t + 512];
}

// =============== fallback: fully fused single kernel (validated round 2) ===============

__device__ inline uint32_t score_int(const Keys& K, uint32_t b, int s,
                                     const uint32_t* cov) {
  uint32_t j = b * (uint32_t)SEQ + (uint32_t)s;
  uint32_t bits = rbits(K.kn0, K.kn1, j);
  return (bits >> 9) + (((cov[s >> 5] >> (s & 31)) & 1u) << 23);
}

__global__ __launch_bounds__(256)
void mask_kernel(const float* __restrict__ feat, const float* __restrict__ tok,
                 float* __restrict__ out, Keys K) {
  __shared__ uint32_t cov[SEQ / 32];
  __shared__ uint32_t fm[SEQ / 32];
  __shared__ uint32_t hist[4096];
  __shared__ uint32_t part[256];
  __shared__ uint32_t sH, sA, sT, sN;

  const int t = threadIdx.x;
  const uint32_t b = blockIdx.x;

  for (int i = t; i < 4096; i += 256) hist[i] = 0u;
  for (int i = t; i < SEQ / 32; i += 256) cov[i] = 0u;
  __syncthreads();

  for (int i = t; i < NSPANS; i += 256) {
    uint32_t j = b * (uint32_t)NSPANS + (uint32_t)i;
    uint32_t lenb = rbits(K.klo0, K.klo1, j);
    uint32_t len = 5u + (lenb & 15u);
    uint32_t hb = rbits(K.khi_s0, K.khi_s1, j);
    uint32_t lb = rbits(K.klo_s0, K.klo_s1, j);
    const uint32_t span = 16379u;
    uint32_t start = ((hb % span) * 400u + (lb % span)) % span;
    uint32_t end = start + len; if (end > (uint32_t)SEQ) end = SEQ;
    uint32_t w0 = start >> 5, w1 = (end - 1u) >> 5;
    for (uint32_t w = w0; w <= w1; ++w) {
      uint32_t bs = (w == w0) ? (start & 31u) : 0u;
      uint32_t be = (w == w1) ? ((end - 1u) & 31u) : 31u;
      uint32_t n = be - bs + 1u;
      uint32_t m = (n >= 32u) ? 0xFFFFFFFFu : (((1u << n) - 1u) << bs);
      atomicOr(&cov[w], m);
    }
  }
  __syncthreads();

  for (int q = 0; q < 64; ++q) {
    uint32_t si = score_int(K, b, t + (q << 8), cov);
    atomicAdd(&hist[si >> 12], 1u);
  }
  __syncthreads();
  {
    uint32_t sum = 0;
#pragma unroll
    for (int i = 0; i < 16; ++i) sum += hist[t * 16 + i];
    part[t] = sum;
    __syncthreads();
    for (int off = 1; off < 256; off <<= 1) {
      uint32_t v = (t + off < 256) ? part[t + off] : 0u;
      __syncthreads();
      part[t] += v;
      __syncthreads();
    }
    uint32_t above = (t < 255) ? part[t + 1] : 0u;
    uint32_t mine = part[t];
    if (above < TGT && TGT <= mine) {
      uint32_t run = above;
      for (int hb = t * 16 + 15; hb >= t * 16; --hb) {
        uint32_t c = hist[hb];
        if (run + c >= TGT) { sH = (uint32_t)hb; sA = run; break; }
        run += c;
      }
    }
  }
  __syncthreads();
  uint32_t H = sH;
  uint32_t targetB = TGT - sA;

  for (int i = t; i < 4096; i += 256) hist[i] = 0u;
  __syncthreads();
  for (int q = 0; q < 64; ++q) {
    uint32_t si = score_int(K, b, t + (q << 8), cov);
    if ((si >> 12) == H) atomicAdd(&hist[si & 4095u], 1u);
  }
  __syncthreads();
  {
    uint32_t sum = 0;
#pragma unroll
    for (int i = 0; i < 16; ++i) sum += hist[t * 16 + i];
    part[t] = sum;
    __syncthreads();
    for (int off = 1; off < 256; off <<= 1) {
      uint32_t v = (t + off < 256) ? part[t + off] : 0u;
      __syncthreads();
      part[t] += v;
      __syncthreads();
    }
    uint32_t above = (t < 255) ? part[t + 1] : 0u;
    uint32_t mine = part[t];
    if (above < targetB && targetB <= mine) {
      uint32_t run = above;
      for (int lb = t * 16 + 15; lb >= t * 16; --lb) {
        uint32_t c = hist[lb];
        if (run + c >= targetB) { sT = (H << 12) | (uint32_t)lb; sN = targetB - run; break; }
        run += c;
      }
    }
  }
  __syncthreads();
  uint32_t T = sT, need = sN;

  const float* rowf = feat + (size_t)b * ROWF;
  {
    int base = t << 6;
    uint32_t cnt = 0;
    for (int i = 0; i < 64; ++i) cnt += (score_int(K, b, base + i, cov) == T) ? 1u : 0u;
    part[t] = cnt;
    __syncthreads();
    for (int off = 1; off < 256; off <<= 1) {
      uint32_t v = (t >= off) ? part[t - off] : 0u;
      __syncthreads();
      part[t] += v;
      __syncthreads();
    }
    uint32_t r = part[t] - cnt;
    uint32_t w0 = 0, w1 = 0;
    for (int i = 0; i < 64; ++i) {
      int s = base + i;
      uint32_t si = score_int(K, b, s, cov);
      bool tie = (si == T);
      bool a = (si > T) || (tie && r < need);
      r += tie ? 1u : 0u;
      float f0 = rowf[s * 6];
      a = a && !(f0 != f0);
      if (i < 32) w0 |= ((uint32_t)a) << i;
      else        w1 |= ((uint32_t)a) << (i - 32);
    }
    fm[2 * t] = w0;
    fm[2 * t + 1] = w1;
  }
  __syncthreads();

  float tk[NF];
#pragma unroll
  for (int c = 0; c < NF; ++c) tk[c] = tok[c];
  float* rowo = out + (size_t)b * ROWF;
  const float4* rf4 = (const float4*)rowf;
  float4* ro4 = (float4*)rowo;
  for (int q = t; q < ROWF4; q += 256) {
    float4 v = rf4[q];
    float vv[4] = {v.x, v.y, v.z, v.w};
    int e = q * 4;
#pragma unroll
    for (int k = 0; k < 4; ++k) {
      int ee = e + k;
      int p = ee / 6;
      int c = ee - p * 6;
      if ((fm[p >> 5] >> (p & 31)) & 1u) vv[k] = tk[c];
    }
    ro4[q] = make_float4(vv[0], vv[1], vv[2], vv[3]);
  }
}

extern "C" void kernel_launch(void* const* d_in, const int* in_sizes, int n_in,
                              void* d_out, int out_size, void* d_ws, size_t ws_size,
                              hipStream_t stream) {
  const float* feat = (const float*)d_in[0];
  const float* tok = (const float*)d_in[1];
  float* out = (float*)d_out;

  // ---- host-side key derivation (partitionable threefry) ----
  // key(1234) -> (0, 1234); split(key,3) foldlike: child i = tf(key, (0, i))
  uint32_t klen0, klen1, kst0, kst1, kn0, kn1;
  tf2x32(0u, 1234u, 0u, 0u, klen0, klen1);   // k_len
  tf2x32(0u, 1234u, 0u, 1u, kst0, kst1);     // k_start
  tf2x32(0u, 1234u, 0u, 2u, kn0, kn1);       // k_noise
  uint32_t lh0, lh1, ll0, ll1;
  tf2x32(klen0, klen1, 0u, 0u, lh0, lh1);    // unused (span=16 pow2)
  tf2x32(klen0, klen1, 0u, 1u, ll0, ll1);
  (void)lh0; (void)lh1;
  uint32_t sh0, sh1, sl0, sl1;
  tf2x32(kst0, kst1, 0u, 0u, sh0, sh1);
  tf2x32(kst0, kst1, 0u, 1u, sl0, sl1);
  Keys K{ ll0, ll1, sh0, sh1, sl0, sl1, kn0, kn1 };

  if (ws_size >= WS_BYTES) {
    uint32_t* ws = (uint32_t*)d_ws;
    hipLaunchKernelGGL(score_hist_kernel, dim3(NB * 4), dim3(256), 0, stream, ws, K);
    hipLaunchKernelGGL(select_kernel, dim3(NB), dim3(256), 0, stream, ws);
    hipLaunchKernelGGL(apply3, dim3(TOT4 / 768), dim3(256), 0, stream,
                       feat, tok, ws, out);
  } else {
    hipLaunchKernelGGL(mask_kernel, dim3(NB), dim3(256), 0, stream, feat, tok, out, K);
  }
}

// Round 7
// 112.316 us; speedup vs baseline: 1.2972x; 1.2972x over previous
//
#include <hip/hip_runtime.h>
#include <stdint.h>

// Problem constants (from reference):
//   features: [128, 16384, 6] f32; mask_token: [6] f32; seed 1234
//   MASK_RATIO=0.15 -> target_masked = int(16384*0.15) = 2457
//   n_spans = max(1, int(2457/12.5*2)) = 393
constexpr int NB = 128;
constexpr int SEQ = 16384;
constexpr int NF = 6;
constexpr int NSPANS = 393;
constexpr uint32_t TGT = 2457u;
constexpr int ROWF = SEQ * NF;          // 98304 floats per row
constexpr int ROWF4 = ROWF / 4;         // 24576 float4 per row
constexpr int TOT4 = NB * ROWF4;        // 3145728 float4 total

// ---- workspace layout (dword offsets) ----
constexpr int FM_OFF = 0;                           // 128*512 final mask bits
constexpr int FM_DW = NB * (SEQ / 32);              // 65536
constexpr size_t WS_BYTES = (size_t)FM_DW * 4;      // 256 KB

struct Keys {
  uint32_t klo0, klo1;     // randint(k_len) child-2 key (span=16 pow2: only lower bits matter)
  uint32_t khi_s0, khi_s1; // randint(k_start) child-1 key -> higher bits
  uint32_t klo_s0, klo_s1; // randint(k_start) child-2 key -> lower bits
  uint32_t kn0, kn1;       // k_noise
};

// JAX threefry2x32 (20 rounds)
__host__ __device__ inline void tf2x32(uint32_t k0, uint32_t k1,
                                       uint32_t x0, uint32_t x1,
                                       uint32_t& o0, uint32_t& o1) {
  uint32_t ks[3] = {k0, k1, k0 ^ k1 ^ 0x1BD11BDAu};
  uint32_t a = x0 + ks[0], b = x1 + ks[1];
  const uint32_t rot[2][4] = {{13u,15u,26u,6u},{17u,29u,16u,24u}};
#pragma unroll
  for (int i = 0; i < 5; ++i) {
    const uint32_t* r = rot[i & 1];
#pragma unroll
    for (int j = 0; j < 4; ++j) {
      a += b;
      b = (b << r[j]) | (b >> (32u - r[j]));
      b ^= a;
    }
    a += ks[(i + 1) % 3];
    b += ks[(i + 2) % 3] + (uint32_t)(i + 1);
  }
  o0 = a; o1 = b;
}

// JAX partitionable random_bits (32-bit): bits[j] = a ^ b, (a,b) = tf(key, (0, j))
__device__ inline uint32_t rbits(uint32_t k0, uint32_t k1, uint32_t j) {
  uint32_t o0, o1;
  tf2x32(k0, k1, 0u, j, o0, o1);
  return o0 ^ o1;
}

// =============== kernel A: mask generation, one block per row, 1024 threads ===============
// All scores live in 16 VGPRs per thread for the whole kernel — zero global
// score traffic (R6 showed cross-block ws traffic dominates; R5 showed even
// same-block ws round-trips cost ~15 µs). LDS: histograms + coverage + fm.
__global__ __launch_bounds__(1024)
void maskgen_kernel(uint32_t* __restrict__ ws, Keys K) {
  __shared__ uint32_t hist[4096];      // 16 KB
  __shared__ uint32_t cov[SEQ / 32];   // 2 KB
  __shared__ uint32_t fm[SEQ / 32];    // 2 KB
  __shared__ uint32_t wsum[16], ssum[16];
  __shared__ int tielist[256];
  __shared__ uint32_t sH, sA, sT, sN;
  __shared__ int tieCnt;

  const int t = threadIdx.x;
  const int lane = t & 63;
  const int wid = t >> 6;
  const uint32_t b = blockIdx.x;

  for (int i = t; i < 4096; i += 1024) hist[i] = 0u;
  if (t < SEQ / 32) cov[t] = 0u;
  if (t == 0) tieCnt = 0;
  __syncthreads();

  // ---- phase 1: spans (one thread per span, LDS atomicOr) ----
  if (t < NSPANS) {
    uint32_t j = b * (uint32_t)NSPANS + (uint32_t)t;
    uint32_t lenb = rbits(K.klo0, K.klo1, j);
    uint32_t len = 5u + (lenb & 15u);
    uint32_t hb = rbits(K.khi_s0, K.khi_s1, j);
    uint32_t lb = rbits(K.klo_s0, K.klo_s1, j);
    const uint32_t span = 16379u;       // 2^32 % 16379 = 400
    uint32_t start = ((hb % span) * 400u + (lb % span)) % span;
    uint32_t end = start + len; if (end > (uint32_t)SEQ) end = SEQ;
    uint32_t w0 = start >> 5, w1 = (end - 1u) >> 5;
    for (uint32_t w = w0; w <= w1; ++w) {
      uint32_t bs = (w == w0) ? (start & 31u) : 0u;
      uint32_t be = (w == w1) ? ((end - 1u) & 31u) : 31u;
      uint32_t n = be - bs + 1u;
      uint32_t m = (n >= 32u) ? 0xFFFFFFFFu : (((1u << n) - 1u) << bs);
      atomicOr(&cov[w], m);
    }
  }
  __syncthreads();

  // ---- phase 2: single threefry pass -> scores in registers + level-1 hist ----
  const uint32_t jb = b << 14;
  uint32_t sr[16];
#pragma unroll
  for (int i = 0; i < 16; ++i) {
    int s = (i << 10) + t;
    uint32_t bits = rbits(K.kn0, K.kn1, jb + (uint32_t)s);
    uint32_t si = (bits >> 9) + (((cov[s >> 5] >> (s & 31)) & 1u) << 23);
    sr[i] = si;
    atomicAdd(&hist[si >> 12], 1u);
  }
  __syncthreads();

  // ---- phase 3: level-1 select via wave-shuffle suffix scan (4 bins/thread) ----
  {
    uint32_t mysum = 0;
#pragma unroll
    for (int i = 0; i < 4; ++i) mysum += hist[t * 4 + i];
    uint32_t v = mysum;
#pragma unroll
    for (int off = 1; off < 64; off <<= 1) {
      uint32_t n = __shfl_down(v, off, 64);
      if (lane + off < 64) v += n;
    }
    if (lane == 0) wsum[wid] = v;   // wave totals
    __syncthreads();
    if (t < 16) {
      uint32_t w = wsum[t];
#pragma unroll
      for (int off = 1; off < 16; off <<= 1) {
        uint32_t n = __shfl_down(w, off, 64);
        if (t + off < 16) w += n;
      }
      ssum[t] = w;                  // inclusive suffix over wave totals
    }
    __syncthreads();
    uint32_t mine = v + (ssum[wid] - wsum[wid]);   // sum of chunks >= mine
    uint32_t above = mine - mysum;                  // strictly above my chunk
    if (above < TGT && TGT <= mine) {
      uint32_t run = above;
      for (int hb = t * 4 + 3; hb >= t * 4; --hb) {
        uint32_t c = hist[hb];
        if (run + c >= TGT) { sH = (uint32_t)hb; sA = run; break; }
        run += c;
      }
    }
  }
  __syncthreads();
  uint32_t H = sH;
  uint32_t targetB = TGT - sA;

  for (int i = t; i < 4096; i += 1024) hist[i] = 0u;
  __syncthreads();

  // ---- phase 4: level-2 histogram from registers ----
#pragma unroll
  for (int i = 0; i < 16; ++i) {
    uint32_t si = sr[i];
    if ((si >> 12) == H) atomicAdd(&hist[si & 4095u], 1u);
  }
  __syncthreads();
  {
    uint32_t mysum = 0;
#pragma unroll
    for (int i = 0; i < 4; ++i) mysum += hist[t * 4 + i];
    uint32_t v = mysum;
#pragma unroll
    for (int off = 1; off < 64; off <<= 1) {
      uint32_t n = __shfl_down(v, off, 64);
      if (lane + off < 64) v += n;
    }
    if (lane == 0) wsum[wid] = v;
    __syncthreads();
    if (t < 16) {
      uint32_t w = wsum[t];
#pragma unroll
      for (int off = 1; off < 16; off <<= 1) {
        uint32_t n = __shfl_down(w, off, 64);
        if (t + off < 16) w += n;
      }
      ssum[t] = w;
    }
    __syncthreads();
    uint32_t mine = v + (ssum[wid] - wsum[wid]);
    uint32_t above = mine - mysum;
    if (above < targetB && targetB <= mine) {
      uint32_t run = above;
      for (int lb = t * 4 + 3; lb >= t * 4; --lb) {
        uint32_t c = hist[lb];
        if (run + c >= targetB) {
          sT = (H << 12) | (uint32_t)lb;
          sN = targetB - run;   // # ties at T accepted (lowest indices first)
          break;
        }
        run += c;
      }
    }
  }
  __syncthreads();
  uint32_t T = sT, need = sN;

  // ---- phase 5: emit bits via ballot from registers; rank ties by index ----
#pragma unroll
  for (int i = 0; i < 16; ++i) {
    int s = (i << 10) + t;
    uint32_t si = sr[i];
    unsigned long long bal = __ballot(si > T);
    if (si == T) {
      int idx = atomicAdd(&tieCnt, 1);
      if (idx < 256) tielist[idx] = s;
    }
    if (lane == 0)       fm[s >> 5] = (uint32_t)bal;
    else if (lane == 32) fm[s >> 5] = (uint32_t)(bal >> 32);
  }
  __syncthreads();
  int tc = tieCnt < 256 ? tieCnt : 256;
  if (t < tc) {
    int s = tielist[t];
    uint32_t rank = 0;
    for (int j = 0; j < tc; ++j) rank += (tielist[j] < s) ? 1u : 0u;
    if (rank < need) atomicOr(&fm[s >> 5], 1u << (s & 31));
  }
  __syncthreads();
  if (t < SEQ / 32) ws[FM_OFF + (b << 9) + t] = fm[t];
}

// =============== kernel B: apply, LDS-staged fully-coalesced (R5-validated) ===============
// Block tile = 768 contiguous float4 (12 KB) = 512 positions; 768 | 24576 so tiles
// never straddle rows. Coalesced load -> LDS; each thread owns 3 consecutive
// float4 = exactly 2 positions (no division); modify in LDS; coalesced store.
__global__ __launch_bounds__(256)
void apply3(const float* __restrict__ feat, const float* __restrict__ tok,
            const uint32_t* __restrict__ ws, float* __restrict__ out) {
  __shared__ float4 tile[768];         // 12 KB
  const int t = threadIdx.x;
  const uint32_t n = blockIdx.x;       // 0..4095
  const float4* f4 = (const float4*)feat + (size_t)n * 768;
  float4* o4 = (float4*)out + (size_t)n * 768;

  tile[t] = f4[t];
  tile[t + 256] = f4[t + 256];
  tile[t + 512] = f4[t + 512];
  uint32_t w = ws[FM_OFF + (n << 4) + (t >> 4)];   // 16 threads share a word
  float t0 = tok[0], t1 = tok[1], t2 = tok[2], t3 = tok[3], t4 = tok[4], t5 = tok[5];
  __syncthreads();

  float* lf = (float*)tile + t * 12;   // my 12 elements = positions p0, p0+1
  uint32_t bit0 = (uint32_t)(2 * t) & 31u;
  bool m0 = (w >> bit0) & 1u;
  bool m1 = (w >> (bit0 + 1u)) & 1u;
  m0 = m0 && !(lf[0] != lf[0]);        // valid = !isnan(channel 0)
  m1 = m1 && !(lf[6] != lf[6]);
  if (m0) { lf[0] = t0; lf[1] = t1; lf[2] = t2; lf[3] = t3; lf[4] = t4; lf[5] = t5; }
  if (m1) { lf[6] = t0; lf[7] = t1; lf[8] = t2; lf[9] = t3; lf[10] = t4; lf[11] = t5; }
  __syncthreads();

  o4[t] = tile[t];
  o4[t + 256] = tile[t + 256];
  o4[t + 512] = tile[t + 512];
}

// =============== fallback: fully fused single kernel (validated round 2) ===============

__device__ inline uint32_t score_int(const Keys& K, uint32_t b, int s,
                                     const uint32_t* cov) {
  uint32_t j = b * (uint32_t)SEQ + (uint32_t)s;
  uint32_t bits = rbits(K.kn0, K.kn1, j);
  return (bits >> 9) + (((cov[s >> 5] >> (s & 31)) & 1u) << 23);
}

__global__ __launch_bounds__(256)
void mask_kernel(const float* __restrict__ feat, const float* __restrict__ tok,
                 float* __restrict__ out, Keys K) {
  __shared__ uint32_t cov[SEQ / 32];
  __shared__ uint32_t fm[SEQ / 32];
  __shared__ uint32_t hist[4096];
  __shared__ uint32_t part[256];
  __shared__ uint32_t sH, sA, sT, sN;

  const int t = threadIdx.x;
  const uint32_t b = blockIdx.x;

  for (int i = t; i < 4096; i += 256) hist[i] = 0u;
  for (int i = t; i < SEQ / 32; i += 256) cov[i] = 0u;
  __syncthreads();

  for (int i = t; i < NSPANS; i += 256) {
    uint32_t j = b * (uint32_t)NSPANS + (uint32_t)i;
    uint32_t lenb = rbits(K.klo0, K.klo1, j);
    uint32_t len = 5u + (lenb & 15u);
    uint32_t hb = rbits(K.khi_s0, K.khi_s1, j);
    uint32_t lb = rbits(K.klo_s0, K.klo_s1, j);
    const uint32_t span = 16379u;
    uint32_t start = ((hb % span) * 400u + (lb % span)) % span;
    uint32_t end = start + len; if (end > (uint32_t)SEQ) end = SEQ;
    uint32_t w0 = start >> 5, w1 = (end - 1u) >> 5;
    for (uint32_t w = w0; w <= w1; ++w) {
      uint32_t bs = (w == w0) ? (start & 31u) : 0u;
      uint32_t be = (w == w1) ? ((end - 1u) & 31u) : 31u;
      uint32_t n = be - bs + 1u;
      uint32_t m = (n >= 32u) ? 0xFFFFFFFFu : (((1u << n) - 1u) << bs);
      atomicOr(&cov[w], m);
    }
  }
  __syncthreads();

  for (int q = 0; q < 64; ++q) {
    uint32_t si = score_int(K, b, t + (q << 8), cov);
    atomicAdd(&hist[si >> 12], 1u);
  }
  __syncthreads();
  {
    uint32_t sum = 0;
#pragma unroll
    for (int i = 0; i < 16; ++i) sum += hist[t * 16 + i];
    part[t] = sum;
    __syncthreads();
    for (int off = 1; off < 256; off <<= 1) {
      uint32_t v = (t + off < 256) ? part[t + off] : 0u;
      __syncthreads();
      part[t] += v;
      __syncthreads();
    }
    uint32_t above = (t < 255) ? part[t + 1] : 0u;
    uint32_t mine = part[t];
    if (above < TGT && TGT <= mine) {
      uint32_t run = above;
      for (int hb = t * 16 + 15; hb >= t * 16; --hb) {
        uint32_t c = hist[hb];
        if (run + c >= TGT) { sH = (uint32_t)hb; sA = run; break; }
        run += c;
      }
    }
  }
  __syncthreads();
  uint32_t H = sH;
  uint32_t targetB = TGT - sA;

  for (int i = t; i < 4096; i += 256) hist[i] = 0u;
  __syncthreads();
  for (int q = 0; q < 64; ++q) {
    uint32_t si = score_int(K, b, t + (q << 8), cov);
    if ((si >> 12) == H) atomicAdd(&hist[si & 4095u], 1u);
  }
  __syncthreads();
  {
    uint32_t sum = 0;
#pragma unroll
    for (int i = 0; i < 16; ++i) sum += hist[t * 16 + i];
    part[t] = sum;
    __syncthreads();
    for (int off = 1; off < 256; off <<= 1) {
      uint32_t v = (t + off < 256) ? part[t + off] : 0u;
      __syncthreads();
      part[t] += v;
      __syncthreads();
    }
    uint32_t above = (t < 255) ? part[t + 1] : 0u;
    uint32_t mine = part[t];
    if (above < targetB && targetB <= mine) {
      uint32_t run = above;
      for (int lb = t * 16 + 15; lb >= t * 16; --lb) {
        uint32_t c = hist[lb];
        if (run + c >= targetB) { sT = (H << 12) | (uint32_t)lb; sN = targetB - run; break; }
        run += c;
      }
    }
  }
  __syncthreads();
  uint32_t T = sT, need = sN;

  const float* rowf = feat + (size_t)b * ROWF;
  {
    int base = t << 6;
    uint32_t cnt = 0;
    for (int i = 0; i < 64; ++i) cnt += (score_int(K, b, base + i, cov) == T) ? 1u : 0u;
    part[t] = cnt;
    __syncthreads();
    for (int off = 1; off < 256; off <<= 1) {
      uint32_t v = (t >= off) ? part[t - off] : 0u;
      __syncthreads();
      part[t] += v;
      __syncthreads();
    }
    uint32_t r = part[t] - cnt;
    uint32_t w0 = 0, w1 = 0;
    for (int i = 0; i < 64; ++i) {
      int s = base + i;
      uint32_t si = score_int(K, b, s, cov);
      bool tie = (si == T);
      bool a = (si > T) || (tie && r < need);
      r += tie ? 1u : 0u;
      float f0 = rowf[s * 6];
      a = a && !(f0 != f0);
      if (i < 32) w0 |= ((uint32_t)a) << i;
      else        w1 |= ((uint32_t)a) << (i - 32);
    }
    fm[2 * t] = w0;
    fm[2 * t + 1] = w1;
  }
  __syncthreads();

  float tk[NF];
#pragma unroll
  for (int c = 0; c < NF; ++c) tk[c] = tok[c];
  float* rowo = out + (size_t)b * ROWF;
  const float4* rf4 = (const float4*)rowf;
  float4* ro4 = (float4*)rowo;
  for (int q = t; q < ROWF4; q += 256) {
    float4 v = rf4[q];
    float vv[4] = {v.x, v.y, v.z, v.w};
    int e = q * 4;
#pragma unroll
    for (int k = 0; k < 4; ++k) {
      int ee = e + k;
      int p = ee / 6;
      int c = ee - p * 6;
      if ((fm[p >> 5] >> (p & 31)) & 1u) vv[k] = tk[c];
    }
    ro4[q] = make_float4(vv[0], vv[1], vv[2], vv[3]);
  }
}

extern "C" void kernel_launch(void* const* d_in, const int* in_sizes, int n_in,
                              void* d_out, int out_size, void* d_ws, size_t ws_size,
                              hipStream_t stream) {
  const float* feat = (const float*)d_in[0];
  const float* tok = (const float*)d_in[1];
  float* out = (float*)d_out;

  // ---- host-side key derivation (partitionable threefry) ----
  // key(1234) -> (0, 1234); split(key,3) foldlike: child i = tf(key, (0, i))
  uint32_t klen0, klen1, kst0, kst1, kn0, kn1;
  tf2x32(0u, 1234u, 0u, 0u, klen0, klen1);   // k_len
  tf2x32(0u, 1234u, 0u, 1u, kst0, kst1);     // k_start
  tf2x32(0u, 1234u, 0u, 2u, kn0, kn1);       // k_noise
  uint32_t lh0, lh1, ll0, ll1;
  tf2x32(klen0, klen1, 0u, 0u, lh0, lh1);    // unused (span=16 pow2)
  tf2x32(klen0, klen1, 0u, 1u, ll0, ll1);
  (void)lh0; (void)lh1;
  uint32_t sh0, sh1, sl0, sl1;
  tf2x32(kst0, kst1, 0u, 0u, sh0, sh1);
  tf2x32(kst0, kst1, 0u, 1u, sl0, sl1);
  Keys K{ ll0, ll1, sh0, sh1, sl0, sl1, kn0, kn1 };

  if (ws_size >= WS_BYTES) {
    uint32_t* ws = (uint32_t*)d_ws;
    hipLaunchKernelGGL(maskgen_kernel, dim3(NB), dim3(1024), 0, stream, ws, K);
    hipLaunchKernelGGL(apply3, dim3(TOT4 / 768), dim3(256), 0, stream,
                       feat, tok, ws, out);
  } else {
    hipLaunchKernelGGL(mask_kernel, dim3(NB), dim3(256), 0, stream, feat, tok, out, K);
  }
}

// Round 8
// 111.547 us; speedup vs baseline: 1.3062x; 1.0069x over previous
//
#include <hip/hip_runtime.h>
#include <stdint.h>

// Problem constants (from reference):
//   features: [128, 16384, 6] f32; mask_token: [6] f32; seed 1234
//   MASK_RATIO=0.15 -> target_masked = int(16384*0.15) = 2457
//   n_spans = max(1, int(2457/12.5*2)) = 393
constexpr int NB = 128;
constexpr int SEQ = 16384;
constexpr int NF = 6;
constexpr int NSPANS = 393;
constexpr uint32_t TGT = 2457u;
constexpr int ROWF = SEQ * NF;          // 98304 floats per row
constexpr int ROWF4 = ROWF / 4;         // 24576 float4 per row
constexpr int TOT4 = NB * ROWF4;        // 3145728 float4 total
constexpr int COPY_BLOCKS = TOT4 / 3072;             // 1024 copy blocks (3 float4/thread)

// ---- workspace layout (dword offsets) ----
constexpr int FM_OFF = 0;                           // 128*512 final mask bits
constexpr int FM_DW = NB * (SEQ / 32);              // 65536
constexpr size_t WS_BYTES = (size_t)FM_DW * 4;      // 256 KB

struct Keys {
  uint32_t klo0, klo1;     // randint(k_len) child-2 key (span=16 pow2: only lower bits matter)
  uint32_t khi_s0, khi_s1; // randint(k_start) child-1 key -> higher bits
  uint32_t klo_s0, klo_s1; // randint(k_start) child-2 key -> lower bits
  uint32_t kn0, kn1;       // k_noise
};

// JAX threefry2x32 (20 rounds)
__host__ __device__ inline void tf2x32(uint32_t k0, uint32_t k1,
                                       uint32_t x0, uint32_t x1,
                                       uint32_t& o0, uint32_t& o1) {
  uint32_t ks[3] = {k0, k1, k0 ^ k1 ^ 0x1BD11BDAu};
  uint32_t a = x0 + ks[0], b = x1 + ks[1];
  const uint32_t rot[2][4] = {{13u,15u,26u,6u},{17u,29u,16u,24u}};
#pragma unroll
  for (int i = 0; i < 5; ++i) {
    const uint32_t* r = rot[i & 1];
#pragma unroll
    for (int j = 0; j < 4; ++j) {
      a += b;
      b = (b << r[j]) | (b >> (32u - r[j]));
      b ^= a;
    }
    a += ks[(i + 1) % 3];
    b += ks[(i + 2) % 3] + (uint32_t)(i + 1);
  }
  o0 = a; o1 = b;
}

// JAX partitionable random_bits (32-bit): bits[j] = a ^ b, (a,b) = tf(key, (0, j))
__device__ inline uint32_t rbits(uint32_t k0, uint32_t k1, uint32_t j) {
  uint32_t o0, o1;
  tf2x32(k0, k1, 0u, j, o0, o1);
  return o0 ^ o1;
}

// =============== fused kernel: blocks 0..127 = maskgen (R7-validated),
//                 blocks 128..1151 = pure streaming copy out=feat ===============
// Copy has NO dependency on the mask; the dispatcher runs both block types
// concurrently across all 256 CUs, hiding maskgen under the copy's BW time.
// A small fixup kernel afterwards rewrites only masked+valid positions.
__global__ __launch_bounds__(1024)
void fused_kernel(const float* __restrict__ feat, float* __restrict__ out,
                  uint32_t* __restrict__ ws, Keys K) {
  __shared__ uint32_t hist[4096];      // 16 KB
  __shared__ uint32_t cov[SEQ / 32];   // 2 KB
  __shared__ uint32_t fm[SEQ / 32];    // 2 KB
  __shared__ uint32_t wsum[16], ssum[16];
  __shared__ int tielist[256];
  __shared__ uint32_t sH, sA, sT, sN;
  __shared__ int tieCnt;

  const int t = threadIdx.x;

  if (blockIdx.x >= (unsigned)NB) {
    // ---------------- copy path: 3 coalesced float4 per thread ----------------
    const uint32_t n = blockIdx.x - NB;          // 0..1023
    const float4* f4 = (const float4*)feat + (size_t)n * 3072;
    float4* o4 = (float4*)out + (size_t)n * 3072;
    o4[t] = f4[t];
    o4[t + 1024] = f4[t + 1024];
    o4[t + 2048] = f4[t + 2048];
    return;
  }

  // ---------------- maskgen path (R7-validated, scores in 16 VGPRs) ----------------
  const int lane = t & 63;
  const int wid = t >> 6;
  const uint32_t b = blockIdx.x;

  for (int i = t; i < 4096; i += 1024) hist[i] = 0u;
  if (t < SEQ / 32) cov[t] = 0u;
  if (t == 0) tieCnt = 0;
  __syncthreads();

  // ---- phase 1: spans (one thread per span, LDS atomicOr) ----
  if (t < NSPANS) {
    uint32_t j = b * (uint32_t)NSPANS + (uint32_t)t;
    uint32_t lenb = rbits(K.klo0, K.klo1, j);
    uint32_t len = 5u + (lenb & 15u);
    uint32_t hb = rbits(K.khi_s0, K.khi_s1, j);
    uint32_t lb = rbits(K.klo_s0, K.klo_s1, j);
    const uint32_t span = 16379u;       // 2^32 % 16379 = 400
    uint32_t start = ((hb % span) * 400u + (lb % span)) % span;
    uint32_t end = start + len; if (end > (uint32_t)SEQ) end = SEQ;
    uint32_t w0 = start >> 5, w1 = (end - 1u) >> 5;
    for (uint32_t w = w0; w <= w1; ++w) {
      uint32_t bs = (w == w0) ? (start & 31u) : 0u;
      uint32_t be = (w == w1) ? ((end - 1u) & 31u) : 31u;
      uint32_t n = be - bs + 1u;
      uint32_t m = (n >= 32u) ? 0xFFFFFFFFu : (((1u << n) - 1u) << bs);
      atomicOr(&cov[w], m);
    }
  }
  __syncthreads();

  // ---- phase 2: single threefry pass -> scores in registers + level-1 hist ----
  const uint32_t jb = b << 14;
  uint32_t sr[16];
#pragma unroll
  for (int i = 0; i < 16; ++i) {
    int s = (i << 10) + t;
    uint32_t bits = rbits(K.kn0, K.kn1, jb + (uint32_t)s);
    uint32_t si = (bits >> 9) + (((cov[s >> 5] >> (s & 31)) & 1u) << 23);
    sr[i] = si;
    atomicAdd(&hist[si >> 12], 1u);
  }
  __syncthreads();

  // ---- phase 3: level-1 select via wave-shuffle suffix scan (4 bins/thread) ----
  {
    uint32_t mysum = 0;
#pragma unroll
    for (int i = 0; i < 4; ++i) mysum += hist[t * 4 + i];
    uint32_t v = mysum;
#pragma unroll
    for (int off = 1; off < 64; off <<= 1) {
      uint32_t n = __shfl_down(v, off, 64);
      if (lane + off < 64) v += n;
    }
    if (lane == 0) wsum[wid] = v;   // wave totals
    __syncthreads();
    if (t < 16) {
      uint32_t w = wsum[t];
#pragma unroll
      for (int off = 1; off < 16; off <<= 1) {
        uint32_t n = __shfl_down(w, off, 64);
        if (t + off < 16) w += n;
      }
      ssum[t] = w;                  // inclusive suffix over wave totals
    }
    __syncthreads();
    uint32_t mine = v + (ssum[wid] - wsum[wid]);   // sum of chunks >= mine
    uint32_t above = mine - mysum;                  // strictly above my chunk
    if (above < TGT && TGT <= mine) {
      uint32_t run = above;
      for (int hb = t * 4 + 3; hb >= t * 4; --hb) {
        uint32_t c = hist[hb];
        if (run + c >= TGT) { sH = (uint32_t)hb; sA = run; break; }
        run += c;
      }
    }
  }
  __syncthreads();
  uint32_t H = sH;
  uint32_t targetB = TGT - sA;

  for (int i = t; i < 4096; i += 1024) hist[i] = 0u;
  __syncthreads();

  // ---- phase 4: level-2 histogram from registers ----
#pragma unroll
  for (int i = 0; i < 16; ++i) {
    uint32_t si = sr[i];
    if ((si >> 12) == H) atomicAdd(&hist[si & 4095u], 1u);
  }
  __syncthreads();
  {
    uint32_t mysum = 0;
#pragma unroll
    for (int i = 0; i < 4; ++i) mysum += hist[t * 4 + i];
    uint32_t v = mysum;
#pragma unroll
    for (int off = 1; off < 64; off <<= 1) {
      uint32_t n = __shfl_down(v, off, 64);
      if (lane + off < 64) v += n;
    }
    if (lane == 0) wsum[wid] = v;
    __syncthreads();
    if (t < 16) {
      uint32_t w = wsum[t];
#pragma unroll
      for (int off = 1; off < 16; off <<= 1) {
        uint32_t n = __shfl_down(w, off, 64);
        if (t + off < 16) w += n;
      }
      ssum[t] = w;
    }
    __syncthreads();
    uint32_t mine = v + (ssum[wid] - wsum[wid]);
    uint32_t above = mine - mysum;
    if (above < targetB && targetB <= mine) {
      uint32_t run = above;
      for (int lb = t * 4 + 3; lb >= t * 4; --lb) {
        uint32_t c = hist[lb];
        if (run + c >= targetB) {
          sT = (H << 12) | (uint32_t)lb;
          sN = targetB - run;   // # ties at T accepted (lowest indices first)
          break;
        }
        run += c;
      }
    }
  }
  __syncthreads();
  uint32_t T = sT, need = sN;

  // ---- phase 5: emit bits via ballot from registers; rank ties by index ----
#pragma unroll
  for (int i = 0; i < 16; ++i) {
    int s = (i << 10) + t;
    uint32_t si = sr[i];
    unsigned long long bal = __ballot(si > T);
    if (si == T) {
      int idx = atomicAdd(&tieCnt, 1);
      if (idx < 256) tielist[idx] = s;
    }
    if (lane == 0)       fm[s >> 5] = (uint32_t)bal;
    else if (lane == 32) fm[s >> 5] = (uint32_t)(bal >> 32);
  }
  __syncthreads();
  int tc = tieCnt < 256 ? tieCnt : 256;
  if (t < tc) {
    int s = tielist[t];
    uint32_t rank = 0;
    for (int j = 0; j < tc; ++j) rank += (tielist[j] < s) ? 1u : 0u;
    if (rank < need) atomicOr(&fm[s >> 5], 1u << (s & 31));
  }
  __syncthreads();
  if (t < SEQ / 32) ws[FM_OFF + (b << 9) + t] = fm[t];
}

// =============== fixup: rewrite masked+valid positions with the token ===============
// One thread per fm word (65536). Avg 4.8 set bits/word; NaN-check ch0, write 6 floats.
__global__ __launch_bounds__(256)
void fixup_kernel(const float* __restrict__ feat, const float* __restrict__ tok,
                  const uint32_t* __restrict__ ws, float* __restrict__ out) {
  int g = blockIdx.x * 256 + threadIdx.x;       // word index, 0..65535
  uint32_t w = ws[FM_OFF + g];
  if (!w) return;
  float t0 = tok[0], t1 = tok[1], t2 = tok[2], t3 = tok[3], t4 = tok[4], t5 = tok[5];
  size_t basePos = (size_t)g * 32;
  while (w) {
    int bit = __ffs(w) - 1;
    w &= w - 1u;
    size_t p = basePos + (size_t)bit;
    float c0 = feat[p * 6];
    if (!(c0 != c0)) {                          // valid = !isnan(channel 0)
      float* o = out + p * 6;
      o[0] = t0; o[1] = t1; o[2] = t2; o[3] = t3; o[4] = t4; o[5] = t5;
    }
  }
}

// =============== fallback: fully fused single kernel (validated round 2) ===============

__device__ inline uint32_t score_int(const Keys& K, uint32_t b, int s,
                                     const uint32_t* cov) {
  uint32_t j = b * (uint32_t)SEQ + (uint32_t)s;
  uint32_t bits = rbits(K.kn0, K.kn1, j);
  return (bits >> 9) + (((cov[s >> 5] >> (s & 31)) & 1u) << 23);
}

__global__ __launch_bounds__(256)
void mask_kernel(const float* __restrict__ feat, const float* __restrict__ tok,
                 float* __restrict__ out, Keys K) {
  __shared__ uint32_t cov[SEQ / 32];
  __shared__ uint32_t fm[SEQ / 32];
  __shared__ uint32_t hist[4096];
  __shared__ uint32_t part[256];
  __shared__ uint32_t sH, sA, sT, sN;

  const int t = threadIdx.x;
  const uint32_t b = blockIdx.x;

  for (int i = t; i < 4096; i += 256) hist[i] = 0u;
  for (int i = t; i < SEQ / 32; i += 256) cov[i] = 0u;
  __syncthreads();

  for (int i = t; i < NSPANS; i += 256) {
    uint32_t j = b * (uint32_t)NSPANS + (uint32_t)i;
    uint32_t lenb = rbits(K.klo0, K.klo1, j);
    uint32_t len = 5u + (lenb & 15u);
    uint32_t hb = rbits(K.khi_s0, K.khi_s1, j);
    uint32_t lb = rbits(K.klo_s0, K.klo_s1, j);
    const uint32_t span = 16379u;
    uint32_t start = ((hb % span) * 400u + (lb % span)) % span;
    uint32_t end = start + len; if (end > (uint32_t)SEQ) end = SEQ;
    uint32_t w0 = start >> 5, w1 = (end - 1u) >> 5;
    for (uint32_t w = w0; w <= w1; ++w) {
      uint32_t bs = (w == w0) ? (start & 31u) : 0u;
      uint32_t be = (w == w1) ? ((end - 1u) & 31u) : 31u;
      uint32_t n = be - bs + 1u;
      uint32_t m = (n >= 32u) ? 0xFFFFFFFFu : (((1u << n) - 1u) << bs);
      atomicOr(&cov[w], m);
    }
  }
  __syncthreads();

  for (int q = 0; q < 64; ++q) {
    uint32_t si = score_int(K, b, t + (q << 8), cov);
    atomicAdd(&hist[si >> 12], 1u);
  }
  __syncthreads();
  {
    uint32_t sum = 0;
#pragma unroll
    for (int i = 0; i < 16; ++i) sum += hist[t * 16 + i];
    part[t] = sum;
    __syncthreads();
    for (int off = 1; off < 256; off <<= 1) {
      uint32_t v = (t + off < 256) ? part[t + off] : 0u;
      __syncthreads();
      part[t] += v;
      __syncthreads();
    }
    uint32_t above = (t < 255) ? part[t + 1] : 0u;
    uint32_t mine = part[t];
    if (above < TGT && TGT <= mine) {
      uint32_t run = above;
      for (int hb = t * 16 + 15; hb >= t * 16; --hb) {
        uint32_t c = hist[hb];
        if (run + c >= TGT) { sH = (uint32_t)hb; sA = run; break; }
        run += c;
      }
    }
  }
  __syncthreads();
  uint32_t H = sH;
  uint32_t targetB = TGT - sA;

  for (int i = t; i < 4096; i += 256) hist[i] = 0u;
  __syncthreads();
  for (int q = 0; q < 64; ++q) {
    uint32_t si = score_int(K, b, t + (q << 8), cov);
    if ((si >> 12) == H) atomicAdd(&hist[si & 4095u], 1u);
  }
  __syncthreads();
  {
    uint32_t sum = 0;
#pragma unroll
    for (int i = 0; i < 16; ++i) sum += hist[t * 16 + i];
    part[t] = sum;
    __syncthreads();
    for (int off = 1; off < 256; off <<= 1) {
      uint32_t v = (t + off < 256) ? part[t + off] : 0u;
      __syncthreads();
      part[t] += v;
      __syncthreads();
    }
    uint32_t above = (t < 255) ? part[t + 1] : 0u;
    uint32_t mine = part[t];
    if (above < targetB && targetB <= mine) {
      uint32_t run = above;
      for (int lb = t * 16 + 15; lb >= t * 16; --lb) {
        uint32_t c = hist[lb];
        if (run + c >= targetB) { sT = (H << 12) | (uint32_t)lb; sN = targetB - run; break; }
        run += c;
      }
    }
  }
  __syncthreads();
  uint32_t T = sT, need = sN;

  const float* rowf = feat + (size_t)b * ROWF;
  {
    int base = t << 6;
    uint32_t cnt = 0;
    for (int i = 0; i < 64; ++i) cnt += (score_int(K, b, base + i, cov) == T) ? 1u : 0u;
    part[t] = cnt;
    __syncthreads();
    for (int off = 1; off < 256; off <<= 1) {
      uint32_t v = (t >= off) ? part[t - off] : 0u;
      __syncthreads();
      part[t] += v;
      __syncthreads();
    }
    uint32_t r = part[t] - cnt;
    uint32_t w0 = 0, w1 = 0;
    for (int i = 0; i < 64; ++i) {
      int s = base + i;
      uint32_t si = score_int(K, b, s, cov);
      bool tie = (si == T);
      bool a = (si > T) || (tie && r < need);
      r += tie ? 1u : 0u;
      float f0 = rowf[s * 6];
      a = a && !(f0 != f0);
      if (i < 32) w0 |= ((uint32_t)a) << i;
      else        w1 |= ((uint32_t)a) << (i - 32);
    }
    fm[2 * t] = w0;
    fm[2 * t + 1] = w1;
  }
  __syncthreads();

  float tk[NF];
#pragma unroll
  for (int c = 0; c < NF; ++c) tk[c] = tok[c];
  float* rowo = out + (size_t)b * ROWF;
  const float4* rf4 = (const float4*)rowf;
  float4* ro4 = (float4*)rowo;
  for (int q = t; q < ROWF4; q += 256) {
    float4 v = rf4[q];
    float vv[4] = {v.x, v.y, v.z, v.w};
    int e = q * 4;
#pragma unroll
    for (int k = 0; k < 4; ++k) {
      int ee = e + k;
      int p = ee / 6;
      int c = ee - p * 6;
      if ((fm[p >> 5] >> (p & 31)) & 1u) vv[k] = tk[c];
    }
    ro4[q] = make_float4(vv[0], vv[1], vv[2], vv[3]);
  }
}

extern "C" void kernel_launch(void* const* d_in, const int* in_sizes, int n_in,
                              void* d_out, int out_size, void* d_ws, size_t ws_size,
                              hipStream_t stream) {
  const float* feat = (const float*)d_in[0];
  const float* tok = (const float*)d_in[1];
  float* out = (float*)d_out;

  // ---- host-side key derivation (partitionable threefry) ----
  // key(1234) -> (0, 1234); split(key,3) foldlike: child i = tf(key, (0, i))
  uint32_t klen0, klen1, kst0, kst1, kn0, kn1;
  tf2x32(0u, 1234u, 0u, 0u, klen0, klen1);   // k_len
  tf2x32(0u, 1234u, 0u, 1u, kst0, kst1);     // k_start
  tf2x32(0u, 1234u, 0u, 2u, kn0, kn1);       // k_noise
  uint32_t lh0, lh1, ll0, ll1;
  tf2x32(klen0, klen1, 0u, 0u, lh0, lh1);    // unused (span=16 pow2)
  tf2x32(klen0, klen1, 0u, 1u, ll0, ll1);
  (void)lh0; (void)lh1;
  uint32_t sh0, sh1, sl0, sl1;
  tf2x32(kst0, kst1, 0u, 0u, sh0, sh1);
  tf2x32(kst0, kst1, 0u, 1u, sl0, sl1);
  Keys K{ ll0, ll1, sh0, sh1, sl0, sl1, kn0, kn1 };

  if (ws_size >= WS_BYTES) {
    uint32_t* ws = (uint32_t*)d_ws;
    hipLaunchKernelGGL(fused_kernel, dim3(NB + COPY_BLOCKS), dim3(1024), 0, stream,
                       feat, out, ws, K);
    hipLaunchKernelGGL(fixup_kernel, dim3(FM_DW / 256), dim3(256), 0, stream,
                       feat, tok, ws, out);
  } else {
    hipLaunchKernelGGL(mask_kernel, dim3(NB), dim3(256), 0, stream, feat, tok, out, K);
  }
}